// Round 17
// baseline (155.063 us; speedup 1.0000x reference)
//
#include <hip/hip_runtime.h>
#include <hip/hip_bf16.h>

#define H_DIM   64
#define T_STEPS 128
#define B_TOT   4096
#define RPW     4     // batch rows per wave (autonomous, barrier-free)
#define RPB     16    // rows per block (4 waves); grid 256 -> 1 block/CU, 1 wave/SIMD
#define NTHREADS 256
#define HST     66    // h LDS row stride in halves (breaks bank alignment)

typedef _Float16 half8  __attribute__((ext_vector_type(8)));
typedef __fp16   fp16x2 __attribute__((ext_vector_type(2)));
typedef __attribute__((ext_vector_type(4))) float f32x4;

#if __has_builtin(__builtin_amdgcn_exp2f)
#define EXP2(x) __builtin_amdgcn_exp2f(x)
#else
#define EXP2(x) exp2f(x)
#endif
#define RCP(x) __builtin_amdgcn_rcpf(x)

// Weights/biases pre-scaled by log2(e) (i,f,o) or 2*log2(e) (g): activations
// are raw exp2-domain. c lives in the 2*log2(e)-scaled domain.
__device__ __forceinline__ float sigmoid2(float xp) {      // xp = x*log2e
    return RCP(1.0f + EXP2(-xp));                          // exact at +-inf
}
__device__ __forceinline__ float tanh2(float xp) {         // xp = 2*log2e*x
    return fmaf(-2.0f, RCP(EXP2(xp) + 1.0f), 1.0f);
}

// pack 8 f32 -> half8 via 4x v_cvt_pkrtz (2 per instruction)
__device__ __forceinline__ half8 cvt8(const float* f) {
    union { unsigned u[4]; half8 h; } r;
#pragma unroll
    for (int i = 0; i < 4; ++i) {
        fp16x2 p = __builtin_amdgcn_cvt_pkrtz(f[2 * i], f[2 * i + 1]);
        r.u[i] = __builtin_bit_cast(unsigned, p);
    }
    return r.h;
}

// BARRIER-FREE LSTM: one wave owns 4 batch rows for all 128 steps.
//
// Placement: rows at M-rows {0,4,8,12} (br = lk). Tiles: (gate g, col-group cg),
// B-frag n=lrow -> output col cg*16+lrow of gate g. C/D row = lk*4+r; the valid
// slot is r=0 for every lk, so lane (lrow,lk) in tile (g,cg) holds gate g of
// site (row=lk, col=cg*16+lrow): ALL 4 gates of a site in one lane across the
// 4 g-tiles -> zero exchange. 4 sites/lane, perfectly balanced over 64 lanes.
//
// h: wave-private LDS patch [4][HST] f16, written at step bottom, read at step
// top (same-wave RAW: program order + in-order DS pipe; compiler fence below).
// x: loaded from global directly in fragment layout (invalid rows duplicate ->
// broadcast), prefetched 1 step ahead into xf registers.
// NO barrier, NO cross-wave traffic in the main loop: waves slip freely.
__global__ __launch_bounds__(NTHREADS, 1) void lstm_fused(
    const int* __restrict__ inst, const float* __restrict__ embed,
    const float* __restrict__ Wih, const float* __restrict__ Whh,
    const float* __restrict__ bih, const float* __restrict__ bhh,
    float* __restrict__ out)
{
    __shared__ int sInst[RPB * T_STEPS];                     // 8 KB
    __shared__ __align__(16) _Float16 sH[4][RPW][HST];       // 2.1 KB (per-wave patches)

    const int tid  = (int)threadIdx.x;
    const int w    = tid >> 6;          // wave 0..3; owns batch rows w*4..w*4+3
    const int l    = tid & 63;
    const int lrow = l & 15;            // A-row (m) / B-frag n / C-col
    const int lk   = l >> 4;            // k-block; ALSO this lane's batch row (br)
    const int b0   = (int)blockIdx.x * RPB;

    const float L2E     = 1.4426950408889634f;
    const float TWO_L2E = 2.8853900817779268f;

    // stage this block's instruction indices (16 rows x 128 steps)
    for (int i = tid; i < RPB * T_STEPS; i += NTHREADS)
        sInst[i] = inst[b0 * T_STEPS + i];

    // zero this wave's h patch (h0 = 0)
    for (int i = l; i < RPW * HST; i += 64)
        ((_Float16*)sH[w])[i] = (_Float16)0.0f;
    __syncthreads();   // the ONLY block barrier (covers sInst + h init)

    // weight B-fragments (f16, exp2-prescaled): wf[g][cg][kf]
    // kf 0,1 -> W_ih k 0..63 ; kf 2,3 -> W_hh k 0..63
    half8 wf[4][4][4];          // 256 VGPR — fits at 1 wave/SIMD (512 budget)
    float bias[4][4];
#pragma unroll
    for (int g = 0; g < 4; ++g) {
        const float ws = (g == 2) ? TWO_L2E : L2E;   // g-gate feeds tanh(2x form)
#pragma unroll
        for (int cg = 0; cg < 4; ++cg) {
            const int gcol = g * 64 + cg * 16 + lrow;     // W output row 0..255
            bias[g][cg] = (bih[gcol] + bhh[gcol]) * ws;
#pragma unroll
            for (int kf = 0; kf < 4; ++kf) {
                const float* src = (kf < 2 ? Wih : Whh) + (long)gcol * H_DIM + (kf & 1) * 32 + lk * 8;
                half8 v;
#pragma unroll
                for (int jj = 0; jj < 8; ++jj) v[jj] = (_Float16)(src[jj] * ws);
                wf[g][cg][kf] = v;
            }
        }
    }

    // x fragment source: lane supplies A[m=lrow][k], x-row = lrow>>2 (rows 1-3
    // of each group duplicate row's data -> harmless garbage C rows)
    const int* myInst = &sInst[(w * RPW + (lrow >> 2)) * T_STEPS];

    float xf[16];   // pending x floats (kf0: k=lk*8.., kf1: k=32+lk*8..); static idx only
    half8 ax0, ax1; // current step's x fragments
    {   // x(0) -> fragments now; x(1) -> xf (pending)
        const float* e0 = embed + (long)myInst[0] * H_DIM + lk * 8;
        *reinterpret_cast<float4*>(&xf[0])  = *reinterpret_cast<const float4*>(e0);
        *reinterpret_cast<float4*>(&xf[4])  = *reinterpret_cast<const float4*>(e0 + 4);
        *reinterpret_cast<float4*>(&xf[8])  = *reinterpret_cast<const float4*>(e0 + 32);
        *reinterpret_cast<float4*>(&xf[12]) = *reinterpret_cast<const float4*>(e0 + 36);
        ax0 = cvt8(&xf[0]);
        ax1 = cvt8(&xf[8]);
        const float* e1 = embed + (long)myInst[1] * H_DIM + lk * 8;
        *reinterpret_cast<float4*>(&xf[0])  = *reinterpret_cast<const float4*>(e1);
        *reinterpret_cast<float4*>(&xf[4])  = *reinterpret_cast<const float4*>(e1 + 4);
        *reinterpret_cast<float4*>(&xf[8])  = *reinterpret_cast<const float4*>(e1 + 32);
        *reinterpret_cast<float4*>(&xf[12]) = *reinterpret_cast<const float4*>(e1 + 36);
    }

    float c[4] = {0.f, 0.f, 0.f, 0.f};   // this lane's 4 sites (row=lk, col=cg*16+lrow)
    float h[4] = {0.f, 0.f, 0.f, 0.f};

#pragma unroll 1
    for (int t = 0; t < T_STEPS; ++t) {
        // h(t) fragments from own patch (rows 1-3 of group duplicate — harmless)
        half8 ah0 = *reinterpret_cast<const half8*>(&sH[w][lrow >> 2][lk * 8]);
        half8 ah1 = *reinterpret_cast<const half8*>(&sH[w][lrow >> 2][32 + lk * 8]);

        // 16 tiles: 4 col-groups x 4 gates; per tile 4-deep MFMA chain.
        // Site update per cg as soon as its 4 gates are ready (ILP across cg).
#pragma unroll
        for (int cg = 0; cg < 4; ++cg) {
            float s[4];
#pragma unroll
            for (int g = 0; g < 4; ++g) {
                f32x4 a = {bias[g][cg], bias[g][cg], bias[g][cg], bias[g][cg]};
                a = __builtin_amdgcn_mfma_f32_16x16x32_f16(ax0, wf[g][cg][0], a, 0, 0, 0);
                a = __builtin_amdgcn_mfma_f32_16x16x32_f16(ax1, wf[g][cg][1], a, 0, 0, 0);
                a = __builtin_amdgcn_mfma_f32_16x16x32_f16(ah0, wf[g][cg][2], a, 0, 0, 0);
                a = __builtin_amdgcn_mfma_f32_16x16x32_f16(ah1, wf[g][cg][3], a, 0, 0, 0);
                s[g] = a[0];          // only C row lk*4 (r=0) is a real site
            }
            const float iv = sigmoid2(s[0]);
            const float fv = sigmoid2(s[1]);
            const float gv = tanh2(s[2]);
            const float ov = sigmoid2(s[3]);
            const float cs = fmaf(fv, c[cg], iv * (gv * TWO_L2E));  // scaled-c domain
            c[cg] = cs;
            h[cg] = ov * tanh2(cs);

            if (t + 1 < T_STEPS)
                sH[w][lk][cg * 16 + lrow] = (_Float16)h[cg];   // publish h(t+1)
        }

        // promote pending x(t+1) floats -> fragments (vmcnt wait inserted here)
        if (t + 1 < T_STEPS) {
            ax0 = cvt8(&xf[0]);
            ax1 = cvt8(&xf[8]);
        }
        // issue x(t+2) loads (a full step of compute hides L2/L3 latency)
        if (t + 2 < T_STEPS) {
            const float* e = embed + (long)myInst[t + 2] * H_DIM + lk * 8;
            *reinterpret_cast<float4*>(&xf[0])  = *reinterpret_cast<const float4*>(e);
            *reinterpret_cast<float4*>(&xf[4])  = *reinterpret_cast<const float4*>(e + 4);
            *reinterpret_cast<float4*>(&xf[8])  = *reinterpret_cast<const float4*>(e + 32);
            *reinterpret_cast<float4*>(&xf[12]) = *reinterpret_cast<const float4*>(e + 36);
        }

        // compiler memory fence: next iteration's LDS reads must not hoist
        // above this iteration's LDS writes (cross-lane RAW is invisible to
        // per-thread alias analysis). Zero-cost; HW DS pipe is in-order per wave.
        asm volatile("" ::: "memory");
    }

    // final h (f32) -> out[B][H]; 4 elements per lane
#pragma unroll
    for (int cg = 0; cg < 4; ++cg)
        out[(long)(b0 + w * RPW + lk) * H_DIM + cg * 16 + lrow] = h[cg];
}

extern "C" void kernel_launch(void* const* d_in, const int* in_sizes, int n_in,
                              void* d_out, int out_size, void* d_ws, size_t ws_size,
                              hipStream_t stream) {
    const int*   inst  = (const int*)  d_in[0];
    const float* embed = (const float*)d_in[1];
    const float* Wih   = (const float*)d_in[2];
    const float* Whh   = (const float*)d_in[3];
    const float* bih   = (const float*)d_in[4];
    const float* bhh   = (const float*)d_in[5];
    float* out = (float*)d_out;

    lstm_fused<<<B_TOT / RPB, NTHREADS, 0, stream>>>(inst, embed, Wih, Whh, bih, bhh, out);
}